// Round 3
// baseline (553.599 us; speedup 1.0000x reference)
//
#include <hip/hip_runtime.h>
#include <hip/hip_bf16.h>
#include <stdint.h>

#define M_DIM 8192
#define IN_F  4096
#define OUT_F 4096
#define NFP   256

typedef __attribute__((ext_vector_type(8))) short short8;   // 8 bf16 = 4 VGPRs
typedef __attribute__((ext_vector_type(4))) float f32x4;

__device__ __forceinline__ void stage16(const void* g, void* l) {
    __builtin_amdgcn_global_load_lds(
        (const __attribute__((address_space(1))) int*)g,
        (__attribute__((address_space(3))) int*)l,
        16, 0, 0);
}

// ---------------------------------------------------------------------------
// Kernel 1: per-row quantization -> bf16.
//   x_scale = amax(|x| over non-outlier cols)/127
//   qx[row][c] = bf16(clip(rint(x/x_scale)))   (0 at outlier cols) -- exact ints
//   act[row][k] = bf16(x[row][ind[k]])         (raw outlier values)
// One block per row, 256 threads, thread t owns cols [t*16, t*16+16).
// ---------------------------------------------------------------------------
__global__ __launch_bounds__(256)
void quant_rows(const float* __restrict__ x,
                const int* __restrict__ ind,
                __hip_bfloat16* __restrict__ qx,
                __hip_bfloat16* __restrict__ act,
                float* __restrict__ xscale)
{
    __shared__ short omap[IN_F];
    __shared__ float red[4];
    __shared__ float s_xs;

    const int t = threadIdx.x;
    const int row = blockIdx.x;

    #pragma unroll
    for (int i = 0; i < IN_F / 256; ++i) omap[t + i * 256] = -1;
    __syncthreads();
    omap[ind[t]] = (short)t;              // NFP == blockDim.x == 256
    __syncthreads();

    const float* xr = x + (size_t)row * IN_F + t * 16;
    float v[16];
    #pragma unroll
    for (int j = 0; j < 4; ++j) {
        float4 f = *(const float4*)(xr + j * 4);
        v[j*4+0] = f.x; v[j*4+1] = f.y; v[j*4+2] = f.z; v[j*4+3] = f.w;
    }
    short om[16];
    #pragma unroll
    for (int j = 0; j < 16; ++j) om[j] = omap[t * 16 + j];

    float m_nz = 0.f;
    #pragma unroll
    for (int j = 0; j < 16; ++j) {
        float a = fabsf(v[j]);
        if (om[j] < 0) m_nz = fmaxf(m_nz, a);
    }
    #pragma unroll
    for (int off = 32; off > 0; off >>= 1)
        m_nz = fmaxf(m_nz, __shfl_down(m_nz, off));
    if ((t & 63) == 0) red[t >> 6] = m_nz;
    __syncthreads();
    if (t == 0) {
        float a = fmaxf(fmaxf(red[0], red[1]), fmaxf(red[2], red[3]));
        xscale[row] = a / 127.0f;                 // exact ref value for epilogue
        s_xs = (a > 0.f) ? (a / 127.0f) : 1.0f;   // guarded divisor
    }
    __syncthreads();
    const float xs = s_xs;

    union { __hip_bfloat16 h[16]; int4 q[2]; } u;
    #pragma unroll
    for (int j = 0; j < 16; ++j) {
        if (om[j] >= 0) {
            act[(size_t)row * NFP + om[j]] = __float2bfloat16(v[j]);
            u.h[j] = __float2bfloat16(0.0f);
        } else {
            float r = rintf(v[j] / xs);           // half-to-even == jnp.round
            r = fminf(fmaxf(r, -128.f), 127.f);
            u.h[j] = __float2bfloat16(r);         // integer <=128: exact in bf16
        }
    }
    int4* dst = (int4*)(qx + (size_t)row * IN_F + t * 16);
    dst[0] = u.q[0];
    dst[1] = u.q[1];
}

// ---------------------------------------------------------------------------
// Kernel 2: weight conversion int32 -> bf16 (exact, |w|<=128) + outlier gather.
// NOTE: harness materializes ALL integer inputs as int32 on device
// ("integer -> const int*") -- q_weight is int32 per element, NOT int8.
// One block per weight row n; thread t owns elements [t*16, t*16+16).
// ---------------------------------------------------------------------------
__global__ __launch_bounds__(256)
void conv_w(const int* __restrict__ qw, const int* __restrict__ ind,
            __hip_bfloat16* __restrict__ wb, __hip_bfloat16* __restrict__ wob)
{
    const int n = blockIdx.x;
    const int t = threadIdx.x;
    const int* src = qw + (size_t)n * IN_F + t * 16;
    union { __hip_bfloat16 h[16]; int4 q[2]; } u;
    #pragma unroll
    for (int j = 0; j < 4; ++j) {
        int4 raw = *(const int4*)(src + j * 4);
        u.h[j*4+0] = __float2bfloat16((float)raw.x);
        u.h[j*4+1] = __float2bfloat16((float)raw.y);
        u.h[j*4+2] = __float2bfloat16((float)raw.z);
        u.h[j*4+3] = __float2bfloat16((float)raw.w);
    }
    int4* dst = (int4*)(wb + (size_t)n * IN_F + t * 16);
    dst[0] = u.q[0];
    dst[1] = u.q[1];
    wob[(size_t)n * NFP + t] =
        __float2bfloat16((float)qw[(size_t)n * IN_F + ind[t]]);
}

// ---------------------------------------------------------------------------
// Kernels 3/4: bf16 NT GEMM (m97-verified structure): 128x128 tile, 4 waves
// (2x2), BK=64, global_load_lds width-16 staging, mfma_f32_16x16x32_bf16.
//   ADD_PREV=false: out = acc * cs[n] + bias[n]
//   ADD_PREV=true : out = acc * rs[row] * cs[n] + out
// Idempotent across calls: GEMM1 overwrites the full output, GEMM2 adds.
// ---------------------------------------------------------------------------
template <bool ADD_PREV>
__global__ __launch_bounds__(256)
void gemm_bf16_nt(const short* __restrict__ A, int lda,
                  const short* __restrict__ B, int ldb,
                  int K,
                  const float* __restrict__ rscale,
                  const float* __restrict__ cscale,
                  const float* __restrict__ bias,
                  float* __restrict__ out, int N)
{
    __shared__ __attribute__((aligned(16))) short As[128 * 64];
    __shared__ __attribute__((aligned(16))) short Bs[128 * 64];

    const int tid = threadIdx.x;
    const int w = tid >> 6, lane = tid & 63;
    const int wm = w >> 1, wn = w & 1;
    const int bm = blockIdx.y * 128, bn = blockIdx.x * 128;
    const int fr = lane & 15, kq = lane >> 4;

    f32x4 acc[4][4] = {};

    const int srow = tid >> 3;          // 0..31
    const int scol = (tid & 7) * 8;     // element offset (16 B)

    const short* gA = A + (size_t)(bm + srow) * lda + scol;
    const short* gB = B + (size_t)(bn + srow) * ldb + scol;
    short* lA = As + w * 512;           // wave-uniform base; HW adds lane*16B
    short* lB = Bs + w * 512;

    for (int k0 = 0; k0 < K; k0 += 64) {
        #pragma unroll
        for (int c = 0; c < 4; ++c) {
            stage16(gA + k0 + (size_t)(c * 32) * lda, lA + c * 2048);
            stage16(gB + k0 + (size_t)(c * 32) * ldb, lB + c * 2048);
        }
        __syncthreads();                 // drains vmcnt; LDS tiles ready

        #pragma unroll
        for (int h = 0; h < 2; ++h) {
            short8 a[4], b[4];
            #pragma unroll
            for (int m = 0; m < 4; ++m)
                a[m] = *(const short8*)&As[(wm * 64 + m * 16 + fr) * 64 + h * 32 + kq * 8];
            #pragma unroll
            for (int n = 0; n < 4; ++n)
                b[n] = *(const short8*)&Bs[(wn * 64 + n * 16 + fr) * 64 + h * 32 + kq * 8];
            #pragma unroll
            for (int m = 0; m < 4; ++m)
                #pragma unroll
                for (int n = 0; n < 4; ++n)
                    acc[m][n] = __builtin_amdgcn_mfma_f32_16x16x32_bf16(
                        a[m], b[n], acc[m][n], 0, 0, 0);
        }
        __syncthreads();                 // reads done before next overwrite
    }

    // epilogue: C/D layout col = lane&15, row = (lane>>4)*4 + reg  [m89-verified]
    #pragma unroll
    for (int m = 0; m < 4; ++m) {
        const int rbase = bm + wm * 64 + m * 16 + kq * 4;
        #pragma unroll
        for (int n = 0; n < 4; ++n) {
            const int col = bn + wn * 64 + n * 16 + fr;
            const float csv = cscale[col];
            const float badd = ADD_PREV ? 0.f : bias[col];
            #pragma unroll
            for (int r = 0; r < 4; ++r) {
                const int row = rbase + r;
                const size_t off = (size_t)row * N + col;
                const float rs = rscale ? rscale[row] : 1.0f;
                float val = acc[m][n][r] * rs * csv;
                if (ADD_PREV) val += out[off];
                else          val += badd;
                out[off] = val;
            }
        }
    }
}

// ---------------------------------------------------------------------------
extern "C" void kernel_launch(void* const* d_in, const int* in_sizes, int n_in,
                              void* d_out, int out_size, void* d_ws, size_t ws_size,
                              hipStream_t stream)
{
    const float* x         = (const float*)d_in[0];
    const int*   q_weight  = (const int*)d_in[1];    // int32 on device!
    const float* scale_col = (const float*)d_in[2];
    const float* bias      = (const float*)d_in[3];
    const int*   ind       = (const int*)d_in[4];
    float*       out       = (float*)d_out;

    // workspace layout (~107 MB)
    __hip_bfloat16* qx  = (__hip_bfloat16*)d_ws;                 // M x IN_F
    __hip_bfloat16* wb  = qx  + (size_t)M_DIM * IN_F;            // OUT_F x IN_F
    __hip_bfloat16* act = wb  + (size_t)OUT_F * IN_F;            // M x NFP
    __hip_bfloat16* wob = act + (size_t)M_DIM * NFP;             // OUT_F x NFP
    float*          xs  = (float*)(wob + (size_t)OUT_F * NFP);   // M

    const size_t need = (size_t)((char*)(xs + M_DIM) - (char*)d_ws);
    if (ws_size < need) return;   // diagnostic: error would read ~2.60e2

    quant_rows<<<dim3(M_DIM), dim3(256), 0, stream>>>(x, ind, qx, act, xs);
    conv_w<<<dim3(OUT_F), dim3(256), 0, stream>>>(q_weight, ind, wb, wob);

    // outlier GEMM (K=256): out = acc * scale_col + bias
    gemm_bf16_nt<false><<<dim3(OUT_F / 128, M_DIM / 128), dim3(256), 0, stream>>>(
        (const short*)act, NFP, (const short*)wob, NFP, NFP,
        nullptr, scale_col, bias, out, OUT_F);

    // main GEMM (K=4096): out += acc * x_scale * scale_col
    gemm_bf16_nt<true><<<dim3(OUT_F / 128, M_DIM / 128), dim3(256), 0, stream>>>(
        (const short*)qx, IN_F, (const short*)wb, IN_F, IN_F,
        xs, scale_col, nullptr, out, OUT_F);
}

// Round 4
// 383.639 us; speedup vs baseline: 1.4430x; 1.4430x over previous
//
#include <hip/hip_runtime.h>
#include <hip/hip_bf16.h>
#include <stdint.h>

#define M_DIM 8192
#define IN_F  4096
#define OUT_F 4096
#define NFP   256

typedef __attribute__((ext_vector_type(8))) short short8;   // 8 bf16 = 4 VGPRs
typedef __attribute__((ext_vector_type(4))) float f32x4;

__device__ __forceinline__ void stage16(const void* g, void* l) {
    __builtin_amdgcn_global_load_lds(
        (const __attribute__((address_space(1))) int*)g,
        (__attribute__((address_space(3))) int*)l,
        16, 0, 0);
}

// ---------------------------------------------------------------------------
// Kernel 1: per-row quantization -> bf16.
//   x_scale = amax(|x| over non-outlier cols)/127   (stored raw for epilogue)
//   qx[row][c]   = bf16(clip(rint(x/x_scale)))  (0 at outlier cols; exact ints)
//   acts[row][k] = bf16(x[row][ind[k]] / x_scale)   <-- pre-divided, so the
//        fused GEMM can use ONE accumulator: epilogue * x_scale restores it.
// One block per row, 256 threads, thread t owns cols [t*16, t*16+16).
// ---------------------------------------------------------------------------
__global__ __launch_bounds__(256)
void quant_rows(const float* __restrict__ x,
                const int* __restrict__ ind,
                __hip_bfloat16* __restrict__ qx,
                __hip_bfloat16* __restrict__ acts,
                float* __restrict__ xscale)
{
    __shared__ short omap[IN_F];
    __shared__ float red[4];
    __shared__ float s_xs;

    const int t = threadIdx.x;
    const int row = blockIdx.x;

    #pragma unroll
    for (int i = 0; i < IN_F / 256; ++i) omap[t + i * 256] = -1;
    __syncthreads();
    omap[ind[t]] = (short)t;              // NFP == blockDim.x == 256
    __syncthreads();

    const float* xr = x + (size_t)row * IN_F + t * 16;
    float v[16];
    #pragma unroll
    for (int j = 0; j < 4; ++j) {
        float4 f = *(const float4*)(xr + j * 4);
        v[j*4+0] = f.x; v[j*4+1] = f.y; v[j*4+2] = f.z; v[j*4+3] = f.w;
    }
    short om[16];
    #pragma unroll
    for (int j = 0; j < 16; ++j) om[j] = omap[t * 16 + j];

    float m_nz = 0.f;
    #pragma unroll
    for (int j = 0; j < 16; ++j) {
        float a = fabsf(v[j]);
        if (om[j] < 0) m_nz = fmaxf(m_nz, a);
    }
    #pragma unroll
    for (int off = 32; off > 0; off >>= 1)
        m_nz = fmaxf(m_nz, __shfl_down(m_nz, off));
    if ((t & 63) == 0) red[t >> 6] = m_nz;
    __syncthreads();
    if (t == 0) {
        float a = fmaxf(fmaxf(red[0], red[1]), fmaxf(red[2], red[3]));
        xscale[row] = a / 127.0f;                 // exact ref value for epilogue
        s_xs = (a > 0.f) ? (a / 127.0f) : 1.0f;   // guarded divisor
    }
    __syncthreads();
    const float xs = s_xs;

    union { __hip_bfloat16 h[16]; int4 q[2]; } u;
    #pragma unroll
    for (int j = 0; j < 16; ++j) {
        if (om[j] >= 0) {
            acts[(size_t)row * NFP + om[j]] = __float2bfloat16(v[j] / xs);
            u.h[j] = __float2bfloat16(0.0f);
        } else {
            float r = rintf(v[j] / xs);           // half-to-even == jnp.round
            r = fminf(fmaxf(r, -128.f), 127.f);
            u.h[j] = __float2bfloat16(r);         // integer <=128: exact in bf16
        }
    }
    int4* dst = (int4*)(qx + (size_t)row * IN_F + t * 16);
    dst[0] = u.q[0];
    dst[1] = u.q[1];
}

// ---------------------------------------------------------------------------
// Kernel 2: weight conversion int32 -> bf16 (exact, |w|<=128) + outlier gather.
// (harness materializes integer inputs as int32 on device)
// ---------------------------------------------------------------------------
__global__ __launch_bounds__(256)
void conv_w(const int* __restrict__ qw, const int* __restrict__ ind,
            __hip_bfloat16* __restrict__ wb, __hip_bfloat16* __restrict__ wob)
{
    const int n = blockIdx.x;
    const int t = threadIdx.x;
    const int* src = qw + (size_t)n * IN_F + t * 16;
    union { __hip_bfloat16 h[16]; int4 q[2]; } u;
    #pragma unroll
    for (int j = 0; j < 4; ++j) {
        int4 raw = *(const int4*)(src + j * 4);
        u.h[j*4+0] = __float2bfloat16((float)raw.x);
        u.h[j*4+1] = __float2bfloat16((float)raw.y);
        u.h[j*4+2] = __float2bfloat16((float)raw.z);
        u.h[j*4+3] = __float2bfloat16((float)raw.w);
    }
    int4* dst = (int4*)(wb + (size_t)n * IN_F + t * 16);
    dst[0] = u.q[0];
    dst[1] = u.q[1];
    wob[(size_t)n * NFP + t] =
        __float2bfloat16((float)qw[(size_t)n * IN_F + ind[t]]);
}

// ---------------------------------------------------------------------------
// Kernel 3: fused bf16 NT GEMM (m97 structure + T2 LDS XOR-swizzle).
//   acc = qx(128xK) . wb(128xK)^T  over K=4096
//       + acts(128x256) . wob(128x256)^T          (outlier ext., same acc)
//   out = acc * xscale[row] * cscale[col] + bias[col]     (pure write)
// Swizzle (both-sides, m201/m173): global_load_lds dest stays LINEAR;
// the per-lane GLOBAL source column is pre-XORed, and ds_read applies the
// same XOR:  colbyte ^= ((row & 7) << 4)  within each 128B row-window.
// ---------------------------------------------------------------------------
__global__ __launch_bounds__(256)
void gemm_fused(const short* __restrict__ A,   // qx,  lda = IN_F
                const short* __restrict__ B,   // wb,  ldb = IN_F
                const short* __restrict__ A2,  // acts, 256
                const short* __restrict__ B2,  // wob,  256
                const float* __restrict__ rscale,
                const float* __restrict__ cscale,
                const float* __restrict__ bias,
                float* __restrict__ out)
{
    __shared__ __attribute__((aligned(16))) short As[128 * 64];
    __shared__ __attribute__((aligned(16))) short Bs[128 * 64];

    const int tid = threadIdx.x;
    const int w = tid >> 6, lane = tid & 63;
    const int wm = w >> 1, wn = w & 1;
    const int bm = blockIdx.y * 128, bn = blockIdx.x * 128;
    const int fr = lane & 15, kq = lane >> 4;

    f32x4 acc[4][4] = {};

    // staging geometry: thread covers (row = tid>>3 [+32 per c-iter],
    // dest col byte = (tid&7)*16); source col byte is pre-swizzled.
    const int sr  = tid >> 3;                    // 0..31
    const int cb  = (tid & 7) * 16;              // dest col byte in [0,128)
    const int scb = cb ^ ((sr & 7) << 4);        // swizzled source col byte

    const char* gA = (const char*)A + ((size_t)(bm + sr) * IN_F) * 2 + scb;
    const char* gB = (const char*)B + ((size_t)(bn + sr) * IN_F) * 2 + scb;
    const char* gA2 = (const char*)A2 + ((size_t)(bm + sr) * NFP) * 2 + scb;
    const char* gB2 = (const char*)B2 + ((size_t)(bn + sr) * NFP) * 2 + scb;

    short* lA = As + w * 512;        // wave-uniform base; HW adds lane*16B
    short* lB = Bs + w * 512;

    const int swz = (fr & 7) << 3;   // ds_read XOR, in shorts (== <<4 bytes)

    auto mfma_tile = [&]() {
        #pragma unroll
        for (int h = 0; h < 2; ++h) {
            short8 a[4], b[4];
            #pragma unroll
            for (int m = 0; m < 4; ++m)
                a[m] = *(const short8*)&As[(wm * 64 + m * 16 + fr) * 64 +
                                           ((h * 32 + kq * 8) ^ swz)];
            #pragma unroll
            for (int n = 0; n < 4; ++n)
                b[n] = *(const short8*)&Bs[(wn * 64 + n * 16 + fr) * 64 +
                                           ((h * 32 + kq * 8) ^ swz)];
            #pragma unroll
            for (int m = 0; m < 4; ++m)
                #pragma unroll
                for (int n = 0; n < 4; ++n)
                    acc[m][n] = __builtin_amdgcn_mfma_f32_16x16x32_bf16(
                        a[m], b[n], acc[m][n], 0, 0, 0);
        }
    };

    // main K loop (K = 4096)
    for (int k0 = 0; k0 < IN_F; k0 += 64) {
        #pragma unroll
        for (int c = 0; c < 4; ++c) {
            stage16(gA + (size_t)k0 * 2 + (size_t)(c * 32) * IN_F * 2, lA + c * 2048);
            stage16(gB + (size_t)k0 * 2 + (size_t)(c * 32) * IN_F * 2, lB + c * 2048);
        }
        __syncthreads();
        mfma_tile();
        __syncthreads();
    }
    // outlier extension (K = 256), same accumulator (A2 pre-divided by xscale)
    for (int k0 = 0; k0 < NFP; k0 += 64) {
        #pragma unroll
        for (int c = 0; c < 4; ++c) {
            stage16(gA2 + (size_t)k0 * 2 + (size_t)(c * 32) * NFP * 2, lA + c * 2048);
            stage16(gB2 + (size_t)k0 * 2 + (size_t)(c * 32) * NFP * 2, lB + c * 2048);
        }
        __syncthreads();
        mfma_tile();
        __syncthreads();
    }

    // epilogue: C/D layout col = lane&15, row = (lane>>4)*4 + reg [m89]
    #pragma unroll
    for (int m = 0; m < 4; ++m) {
        const int rbase = bm + wm * 64 + m * 16 + kq * 4;
        #pragma unroll
        for (int n = 0; n < 4; ++n) {
            const int col = bn + wn * 64 + n * 16 + fr;
            const float csv = cscale[col];
            const float badd = bias[col];
            #pragma unroll
            for (int r = 0; r < 4; ++r) {
                const int row = rbase + r;
                out[(size_t)row * OUT_F + col] =
                    acc[m][n][r] * rscale[row] * csv + badd;
            }
        }
    }
}

// ---------------------------------------------------------------------------
extern "C" void kernel_launch(void* const* d_in, const int* in_sizes, int n_in,
                              void* d_out, int out_size, void* d_ws, size_t ws_size,
                              hipStream_t stream)
{
    const float* x         = (const float*)d_in[0];
    const int*   q_weight  = (const int*)d_in[1];    // int32 on device!
    const float* scale_col = (const float*)d_in[2];
    const float* bias      = (const float*)d_in[3];
    const int*   ind       = (const int*)d_in[4];
    float*       out       = (float*)d_out;

    // workspace layout (~107 MB)
    __hip_bfloat16* qx   = (__hip_bfloat16*)d_ws;                // M x IN_F
    __hip_bfloat16* wb   = qx   + (size_t)M_DIM * IN_F;          // OUT_F x IN_F
    __hip_bfloat16* acts = wb   + (size_t)OUT_F * IN_F;          // M x NFP
    __hip_bfloat16* wob  = acts + (size_t)M_DIM * NFP;           // OUT_F x NFP
    float*          xs   = (float*)(wob + (size_t)OUT_F * NFP);  // M

    const size_t need = (size_t)((char*)(xs + M_DIM) - (char*)d_ws);
    if (ws_size < need) return;

    quant_rows<<<dim3(M_DIM), dim3(256), 0, stream>>>(x, ind, qx, acts, xs);
    conv_w<<<dim3(OUT_F), dim3(256), 0, stream>>>(q_weight, ind, wb, wob);

    gemm_fused<<<dim3(OUT_F / 128, M_DIM / 128), dim3(256), 0, stream>>>(
        (const short*)qx, (const short*)wb,
        (const short*)acts, (const short*)wob,
        xs, scale_col, bias, out);
}

// Round 5
// 312.396 us; speedup vs baseline: 1.7721x; 1.2281x over previous
//
#include <hip/hip_runtime.h>
#include <hip/hip_bf16.h>
#include <stdint.h>

#define M_DIM 8192
#define IN_F  4096
#define OUT_F 4096
#define NFP   256
#define KTOT  4352            // IN_F + NFP merged K
#define NT    (KTOT / 64)     // 68 K-tiles

typedef __attribute__((ext_vector_type(8))) short short8;   // 8 bf16
typedef __attribute__((ext_vector_type(4))) float f32x4;

__device__ __forceinline__ void stage16(const void* g, void* l) {
    __builtin_amdgcn_global_load_lds(
        (const __attribute__((address_space(1))) int*)g,
        (__attribute__((address_space(3))) int*)l,
        16, 0, 0);
}

#define SB() __builtin_amdgcn_sched_barrier(0)
#define BARRIER() do { SB(); __builtin_amdgcn_s_barrier(); SB(); } while (0)

// ---------------------------------------------------------------------------
// Kernel 1: per-row quantization -> bf16, merged-K layout [4096 q | 256 acts].
// ---------------------------------------------------------------------------
__global__ __launch_bounds__(256)
void quant_rows(const float* __restrict__ x,
                const int* __restrict__ ind,
                __hip_bfloat16* __restrict__ qx,      // M x KTOT
                float* __restrict__ xscale)
{
    __shared__ short omap[IN_F];
    __shared__ float red[4];
    __shared__ float s_xs;

    const int t = threadIdx.x;
    const int row = blockIdx.x;

    #pragma unroll
    for (int i = 0; i < IN_F / 256; ++i) omap[t + i * 256] = -1;
    __syncthreads();
    omap[ind[t]] = (short)t;
    __syncthreads();

    const float* xr = x + (size_t)row * IN_F + t * 16;
    float v[16];
    #pragma unroll
    for (int j = 0; j < 4; ++j) {
        float4 f = *(const float4*)(xr + j * 4);
        v[j*4+0] = f.x; v[j*4+1] = f.y; v[j*4+2] = f.z; v[j*4+3] = f.w;
    }
    short om[16];
    #pragma unroll
    for (int j = 0; j < 16; ++j) om[j] = omap[t * 16 + j];

    float m_nz = 0.f;
    #pragma unroll
    for (int j = 0; j < 16; ++j) {
        float a = fabsf(v[j]);
        if (om[j] < 0) m_nz = fmaxf(m_nz, a);
    }
    #pragma unroll
    for (int off = 32; off > 0; off >>= 1)
        m_nz = fmaxf(m_nz, __shfl_down(m_nz, off));
    if ((t & 63) == 0) red[t >> 6] = m_nz;
    __syncthreads();
    if (t == 0) {
        float a = fmaxf(fmaxf(red[0], red[1]), fmaxf(red[2], red[3]));
        xscale[row] = a / 127.0f;
        s_xs = (a > 0.f) ? (a / 127.0f) : 1.0f;
    }
    __syncthreads();
    const float xs = s_xs;

    __hip_bfloat16* qrow = qx + (size_t)row * KTOT;
    union { __hip_bfloat16 h[16]; int4 q[2]; } u;
    #pragma unroll
    for (int j = 0; j < 16; ++j) {
        if (om[j] >= 0) {
            qrow[IN_F + om[j]] = __float2bfloat16(v[j] / xs);  // acts (pre-div)
            u.h[j] = __float2bfloat16(0.0f);
        } else {
            float r = rintf(v[j] / xs);               // half-to-even == jnp.round
            r = fminf(fmaxf(r, -128.f), 127.f);
            u.h[j] = __float2bfloat16(r);             // exact integer in bf16
        }
    }
    int4* dst = (int4*)(qrow + t * 16);
    dst[0] = u.q[0];
    dst[1] = u.q[1];
}

// ---------------------------------------------------------------------------
// Kernel 2: weight int32 -> bf16 (exact) + outlier gather, merged-K layout.
// ---------------------------------------------------------------------------
__global__ __launch_bounds__(256)
void conv_w(const int* __restrict__ qw, const int* __restrict__ ind,
            __hip_bfloat16* __restrict__ wb)          // OUT_F x KTOT
{
    const int n = blockIdx.x;
    const int t = threadIdx.x;
    const int* src = qw + (size_t)n * IN_F + t * 16;
    __hip_bfloat16* wrow = wb + (size_t)n * KTOT;
    union { __hip_bfloat16 h[16]; int4 q[2]; } u;
    #pragma unroll
    for (int j = 0; j < 4; ++j) {
        int4 raw = *(const int4*)(src + j * 4);
        u.h[j*4+0] = __float2bfloat16((float)raw.x);
        u.h[j*4+1] = __float2bfloat16((float)raw.y);
        u.h[j*4+2] = __float2bfloat16((float)raw.z);
        u.h[j*4+3] = __float2bfloat16((float)raw.w);
    }
    int4* dst = (int4*)(wrow + t * 16);
    dst[0] = u.q[0];
    dst[1] = u.q[1];
    wrow[IN_F + t] = __float2bfloat16((float)qw[(size_t)n * IN_F + ind[t]]);
}

// ---------------------------------------------------------------------------
// Kernel 3: 256x256 8-phase bf16 NT GEMM (T1+T2+T3+T4+T5), K = 4352.
// 8 waves (2M x 4N), BK=64. LDS 128KB: 2 bufs x {Ah0,Ah1,Bh0,Bh1} x 16KB.
// Per tile: 4 phases {reads 8/4/8/4 x b128; stage Ah0(t+1)/Ah1(t+1)/-/Bh0+Bh1(t+2);
// barrier; setprio(1); 16 MFMA; setprio(0); barrier}. vmcnt(4) at tile end only.
// Region-safety: B-halves of buf c freed by P3 reads -> staged at P4; A(t+1)
// goes to the other buffer (idle since t-1). All stage-issues barrier-
// separated from last reads of their region.
// ---------------------------------------------------------------------------
#define LOADA(MB, KK) \
    { _Pragma("unroll") for (int i = 0; i < 4; ++i) \
        af[i] = *(const short8*)&Abuf[(((MB)+i)*16 + fr)*64 + ((((KK)*32) + kq4*8) ^ rsw)]; }

#define LOADB(KK) \
    { _Pragma("unroll") for (int n = 0; n < 4; ++n) \
        bf[n] = *(const short8*)&Bbuf[(wn1*64 + n*16 + fr)*64 + ((((KK)*32) + kq4*8) ^ rsw)]; }

#define MFMA16(MB) \
    { _Pragma("unroll") for (int i = 0; i < 4; ++i) \
      _Pragma("unroll") for (int n = 0; n < 4; ++n) \
        acc[(MB)+i][n] = __builtin_amdgcn_mfma_f32_16x16x32_bf16(af[i], bf[n], acc[(MB)+i][n], 0, 0, 0); }

__global__ __launch_bounds__(512, 2)
void gemm8(const short* __restrict__ A,   // qx,  M x KTOT
           const short* __restrict__ B,   // wb,  OUT_F x KTOT
           const float* __restrict__ rscale,
           const float* __restrict__ cscale,
           const float* __restrict__ bias,
           float* __restrict__ out)
{
    __shared__ __attribute__((aligned(16))) short smem[65536];   // 128 KiB

    const int tid = threadIdx.x;
    const int wv = tid >> 6, lane = tid & 63;
    const int wm = wv >> 2, wn = wv & 3;
    const int wn1 = wn & 1, whb = wn >> 1;
    const int fr = lane & 15, kq4 = lane >> 4;
    const int rsw = (fr & 7) << 3;               // read-side XOR (shorts)

    // XCD-aware bijective swizzle (512 blocks, 512%8==0)
    const int bid = blockIdx.x;
    const int lin = (bid & 7) * 64 + (bid >> 3);
    const int bm = (lin & 31) * 256;             // M tile
    const int bn = (lin >> 5) * 256;             // N tile

    // staging geometry: thread covers local row srow (+64 for op1), 16B col cb
    const int srow = tid >> 3;                   // 0..63
    const int cb   = (tid & 7) * 16;
    const int scb  = cb ^ ((srow & 7) << 4);     // pre-swizzled source col byte

    const size_t ldbyte = (size_t)KTOT * 2;      // 8704 B row stride

    auto stageA = [&](int T, int h, int c) {
        const char* src = (const char*)A + (size_t)(bm + h * 128 + srow) * ldbyte
                        + (size_t)T * 128 + scb;
        char* dst = (char*)smem + c * 65536 + h * 16384 + wv * 1024;
        stage16(src, dst);
        stage16(src + 64 * ldbyte, dst + 8192);
    };
    auto stageB = [&](int T, int h, int c) {
        const char* src = (const char*)B + (size_t)(bn + h * 128 + srow) * ldbyte
                        + (size_t)T * 128 + scb;
        char* dst = (char*)smem + c * 65536 + 32768 + h * 16384 + wv * 1024;
        stage16(src, dst);
        stage16(src + 64 * ldbyte, dst + 8192);
    };

    f32x4 acc[8][4] = {};
    short8 af[4], bf[4];

    // prologue: tile0 {Bh0,Bh1,Ah0,Ah1} + tile1 {Bh0,Bh1}; keep newest 4 in flight
    stageB(0, 0, 0); stageB(0, 1, 0);
    stageA(0, 0, 0); stageA(0, 1, 0);
    stageB(1, 0, 1); stageB(1, 1, 1);
    SB();
    asm volatile("s_waitcnt vmcnt(4)" ::: "memory");
    BARRIER();

    for (int t = 0; t < NT; ++t) {
        const int c = t & 1;
        const short* Abuf = smem + c * 32768 + wm * 8192;
        const short* Bbuf = smem + c * 32768 + 16384 + whb * 8192;

        // ---- P1: A m0-3 k0 + B k0 (8 reads); stage A(t+1)h0 -> buf c^1 ----
        LOADB(0);
        LOADA(0, 0);
        if (t + 1 < NT) stageA(t + 1, 0, c ^ 1);
        BARRIER();
        __builtin_amdgcn_s_setprio(1);
        MFMA16(0);
        __builtin_amdgcn_s_setprio(0);
        BARRIER();

        // ---- P2: A m4-7 k0 (4 reads); stage A(t+1)h1 ----
        LOADA(4, 0);
        if (t + 1 < NT) stageA(t + 1, 1, c ^ 1);
        BARRIER();
        __builtin_amdgcn_s_setprio(1);
        MFMA16(4);
        __builtin_amdgcn_s_setprio(0);
        BARRIER();

        // ---- P3: A m0-3 k1 + B k1 (8 reads); no stage ----
        LOADB(1);
        LOADA(0, 1);
        BARRIER();
        __builtin_amdgcn_s_setprio(1);
        MFMA16(0);
        __builtin_amdgcn_s_setprio(0);
        BARRIER();

        // ---- P4: A m4-7 k1 (4 reads); stage B(t+2)h0,h1 -> buf c (freed @P4) ----
        LOADA(4, 1);
        if (t + 2 < NT) { stageB(t + 2, 0, c); stageB(t + 2, 1, c); }
        BARRIER();
        __builtin_amdgcn_s_setprio(1);
        MFMA16(4);
        __builtin_amdgcn_s_setprio(0);
        SB();
        // tile boundary: land tile t+1 (newest 4 loads = B(t+2) may stay in flight)
        if (t < NT - 2)       asm volatile("s_waitcnt vmcnt(4)" ::: "memory");
        else if (t == NT - 2) asm volatile("s_waitcnt vmcnt(0)" ::: "memory");
        BARRIER();
    }

    // epilogue: C/D layout col = lane&15, row = (lane>>4)*4 + reg [m89]
    #pragma unroll
    for (int m = 0; m < 8; ++m) {
        const int rbase = bm + wm * 128 + m * 16 + kq4 * 4;
        #pragma unroll
        for (int n = 0; n < 4; ++n) {
            const int col = bn + wn * 64 + n * 16 + fr;
            const float csv = cscale[col];
            const float badd = bias[col];
            #pragma unroll
            for (int r = 0; r < 4; ++r) {
                const int row = rbase + r;
                out[(size_t)row * OUT_F + col] =
                    acc[m][n][r] * rscale[row] * csv + badd;
            }
        }
    }
}

// ---------------------------------------------------------------------------
extern "C" void kernel_launch(void* const* d_in, const int* in_sizes, int n_in,
                              void* d_out, int out_size, void* d_ws, size_t ws_size,
                              hipStream_t stream)
{
    const float* x         = (const float*)d_in[0];
    const int*   q_weight  = (const int*)d_in[1];    // int32 on device
    const float* scale_col = (const float*)d_in[2];
    const float* bias      = (const float*)d_in[3];
    const int*   ind       = (const int*)d_in[4];
    float*       out       = (float*)d_out;

    // workspace (~107 MB): qx (M x KTOT bf16), wb (OUT_F x KTOT bf16), xscale
    __hip_bfloat16* qx = (__hip_bfloat16*)d_ws;
    __hip_bfloat16* wb = qx + (size_t)M_DIM * KTOT;
    float*          xs = (float*)(wb + (size_t)OUT_F * KTOT);

    const size_t need = (size_t)((char*)(xs + M_DIM) - (char*)d_ws);
    if (ws_size < need) return;

    quant_rows<<<dim3(M_DIM), dim3(256), 0, stream>>>(x, ind, qx, xs);
    conv_w<<<dim3(OUT_F), dim3(256), 0, stream>>>(q_weight, ind, wb);

    gemm8<<<dim3((M_DIM / 256) * (OUT_F / 256)), dim3(512), 0, stream>>>(
        (const short*)qx, (const short*)wb, xs, scale_col, bias, out);
}

// Round 6
// 275.750 us; speedup vs baseline: 2.0076x; 1.1329x over previous
//
#include <hip/hip_runtime.h>
#include <hip/hip_bf16.h>
#include <stdint.h>

#define M_DIM 8192
#define IN_F  4096
#define OUT_F 4096
#define NFP   256
#define NTI   64              // i8 K-tiles (4096/64)

typedef __attribute__((ext_vector_type(4)))  int   v4i;
typedef __attribute__((ext_vector_type(16))) int   v16i;
typedef __attribute__((ext_vector_type(16))) float v16f;
typedef __attribute__((ext_vector_type(8)))  short short8;

__device__ __forceinline__ void stage16(const void* g, void* l) {
    __builtin_amdgcn_global_load_lds(
        (const __attribute__((address_space(1))) int*)g,
        (__attribute__((address_space(3))) int*)l,
        16, 0, 0);
}

#define SB() __builtin_amdgcn_sched_barrier(0)

// ---------------------------------------------------------------------------
// Kernel 1: per-row quantization.
//   x_scale = amax(|x| over non-outlier cols)/127
//   qx[row][c]  = int8(clip(rint(x/xs)))  (0 at outlier cols)       M x 4096
//   acts[row][k]= bf16(x[row][ind[k]] / xs)  (pre-divided)          M x 256
// ---------------------------------------------------------------------------
__global__ __launch_bounds__(256)
void quant_rows(const float* __restrict__ x,
                const int* __restrict__ ind,
                char* __restrict__ qx,
                __hip_bfloat16* __restrict__ acts,
                float* __restrict__ xscale)
{
    __shared__ short omap[IN_F];
    __shared__ float red[4];
    __shared__ float s_xs;

    const int t = threadIdx.x;
    const int row = blockIdx.x;

    #pragma unroll
    for (int i = 0; i < IN_F / 256; ++i) omap[t + i * 256] = -1;
    __syncthreads();
    omap[ind[t]] = (short)t;
    __syncthreads();

    const float* xr = x + (size_t)row * IN_F + t * 16;
    float v[16];
    #pragma unroll
    for (int j = 0; j < 4; ++j) {
        float4 f = *(const float4*)(xr + j * 4);
        v[j*4+0] = f.x; v[j*4+1] = f.y; v[j*4+2] = f.z; v[j*4+3] = f.w;
    }
    short om[16];
    #pragma unroll
    for (int j = 0; j < 16; ++j) om[j] = omap[t * 16 + j];

    float m_nz = 0.f;
    #pragma unroll
    for (int j = 0; j < 16; ++j) {
        float a = fabsf(v[j]);
        if (om[j] < 0) m_nz = fmaxf(m_nz, a);
    }
    #pragma unroll
    for (int off = 32; off > 0; off >>= 1)
        m_nz = fmaxf(m_nz, __shfl_down(m_nz, off));
    if ((t & 63) == 0) red[t >> 6] = m_nz;
    __syncthreads();
    if (t == 0) {
        float a = fmaxf(fmaxf(red[0], red[1]), fmaxf(red[2], red[3]));
        xscale[row] = a / 127.0f;
        s_xs = (a > 0.f) ? (a / 127.0f) : 1.0f;
    }
    __syncthreads();
    const float xs = s_xs;

    union { char c[16]; int4 q; } u;
    #pragma unroll
    for (int j = 0; j < 16; ++j) {
        if (om[j] >= 0) {
            acts[(size_t)row * NFP + om[j]] = __float2bfloat16(v[j] / xs);
            u.c[j] = 0;
        } else {
            float r = rintf(v[j] / xs);               // half-to-even == jnp.round
            r = fminf(fmaxf(r, -128.f), 127.f);
            u.c[j] = (char)(int)r;
        }
    }
    *(int4*)(qx + (size_t)row * IN_F + t * 16) = u.q;
}

// ---------------------------------------------------------------------------
// Kernel 2: weight int32 -> int8 (exact) + outlier-column gather -> bf16.
// ---------------------------------------------------------------------------
__global__ __launch_bounds__(256)
void conv_w(const int* __restrict__ qw, const int* __restrict__ ind,
            char* __restrict__ qb, __hip_bfloat16* __restrict__ wob)
{
    const int n = blockIdx.x;
    const int t = threadIdx.x;
    const int* src = qw + (size_t)n * IN_F + t * 16;
    union { char c[16]; int4 q; } u;
    #pragma unroll
    for (int j = 0; j < 4; ++j) {
        int4 raw = *(const int4*)(src + j * 4);
        u.c[j*4+0] = (char)raw.x; u.c[j*4+1] = (char)raw.y;
        u.c[j*4+2] = (char)raw.z; u.c[j*4+3] = (char)raw.w;
    }
    *(int4*)(qb + (size_t)n * IN_F + t * 16) = u.q;
    wob[(size_t)n * NFP + t] = __float2bfloat16((float)qw[(size_t)n * IN_F + ind[t]]);
}

// ---------------------------------------------------------------------------
// Kernel 3: fused 256x256 GEMM.
//   Phase 1 (64 tiles): int8 mfma_i32_32x32x32_i8, exact i32 acc.
//     LDS kgroup-major [kgroup][row][16B] -> conflict-free staging AND reads.
//     3 buffers x 32KB, prefetch distance 2, ONE {lgkmcnt0; vmcnt(4); barrier}
//     per tile (no mid-tile barriers; waves free-run -> LDS/MFMA overlap).
//   Phase 2 (4 tiles): bf16 mfma_f32_32x32x16_bf16 outlier extension into the
//     converted f32 accumulator (acts pre-divided by x_scale).
//   Epilogue: out = acc * xscale[row] * cscale[col] + bias[col].
// 8 waves (2M x 4N); per-wave output 128x64.
// ---------------------------------------------------------------------------
__global__ __launch_bounds__(512, 2)
void gemm_mix(const char* __restrict__ Aq, const char* __restrict__ Bq,
              const short* __restrict__ Ab, const short* __restrict__ Bb,
              const float* __restrict__ rscale,
              const float* __restrict__ cscale,
              const float* __restrict__ bias,
              float* __restrict__ out)
{
    __shared__ __attribute__((aligned(16))) char smem[98304];   // 3 x 32KB

    const int tid = threadIdx.x;
    const int wv = tid >> 6, lane = tid & 63;
    const int wm = wv >> 2, wn = wv & 3;
    const int l31 = lane & 31, kh = lane >> 5;

    // XCD-aware bijective swizzle (512 blocks, 512 % 8 == 0)
    const int bid = blockIdx.x;
    const int lin = (bid & 7) * 64 + (bid >> 3);
    const int bm = (lin & 31) * 256;
    const int bn = (lin >> 5) * 256;

    // ---- i8 staging: tile = A 16KB + B 16KB; 32 chunks of 1024B ----
    // A chunk ca in [0,16): half hA=ca>>3, kgroup g=(ca>>1)&3, rowhalf rh=ca&1
    // wave wv stages ca = wv and ca = wv+8 for both A and B (4 stage16/wave).
    auto stage_i8 = [&](int t, int buf) {
        #pragma unroll
        for (int j = 0; j < 2; ++j) {
            const int ca = wv + j * 8;
            const int hA = ca >> 3, g = (ca >> 1) & 3, rh = ca & 1;
            const size_t grow = (size_t)(hA * 128 + rh * 64 + lane);
            const int gcol = t * 64 + g * 16;
            stage16(Aq + (size_t)(bm + grow) * IN_F + gcol,
                    smem + buf * 32768 + ca * 1024);
            stage16(Bq + (size_t)(bn + grow) * IN_F + gcol,
                    smem + buf * 32768 + 16384 + ca * 1024);
        }
    };

    v16i acci[4][2] = {};

    // prologue: tiles 0,1 staged; tile0 ready after vmcnt(4)
    stage_i8(0, 0);
    stage_i8(1, 1);
    SB();
    asm volatile("s_waitcnt vmcnt(4)" ::: "memory");
    __builtin_amdgcn_s_barrier();
    SB();

    for (int t = 0; t < NTI; ++t) {
        const int ct = t % 3;
        if (t + 2 < NTI) stage_i8(t + 2, (t + 2) % 3);

        const char* Abuf = smem + ct * 32768 + wm * 8192;
        const char* Bbuf = smem + ct * 32768 + 16384 + (wn >> 1) * 8192;
        const int coff = ((wn & 1) * 64) * 16;

        #pragma unroll
        for (int ks = 0; ks < 2; ++ks) {
            v4i a[4], b[2];
            const int gk = (ks * 2 + kh) * 2048;
            #pragma unroll
            for (int m = 0; m < 4; ++m)
                a[m] = *(const v4i*)(Abuf + gk + (m * 32 + l31) * 16);
            #pragma unroll
            for (int n = 0; n < 2; ++n)
                b[n] = *(const v4i*)(Bbuf + gk + coff + (n * 32 + l31) * 16);
            __builtin_amdgcn_s_setprio(1);
            #pragma unroll
            for (int m = 0; m < 4; ++m)
                #pragma unroll
                for (int n = 0; n < 2; ++n)
                    acci[m][n] = __builtin_amdgcn_mfma_i32_32x32x32_i8(
                        a[m], b[n], acci[m][n], 0, 0, 0);
            __builtin_amdgcn_s_setprio(0);
        }
        SB();
        asm volatile("s_waitcnt lgkmcnt(0)" ::: "memory");   // our reads done
        if (t < NTI - 2) asm volatile("s_waitcnt vmcnt(4)" ::: "memory");
        else             asm volatile("s_waitcnt vmcnt(0)" ::: "memory");
        __builtin_amdgcn_s_barrier();
        SB();
    }

    // convert exact i32 acc -> f32 (per-frag so regalloc can overlap lifetimes)
    v16f accf[4][2];
    #pragma unroll
    for (int m = 0; m < 4; ++m)
        #pragma unroll
        for (int n = 0; n < 2; ++n)
            #pragma unroll
            for (int r = 0; r < 16; ++r)
                accf[m][n][r] = (float)acci[m][n][r];

    // ---- Phase 2: bf16 outlier tiles (K = 256 = 4 x 64), single-buffered ----
    // tile = A 32KB @0 + B 32KB @32768; layout [half][kgroup(8)][row(128)][16B]
    for (int to = 0; to < 4; ++to) {
        #pragma unroll
        for (int j = 0; j < 4; ++j) {
            const int ca = wv * 4 + j;
            const int hA = ca >> 4, g = (ca >> 1) & 7, rh = ca & 1;
            const size_t grow = (size_t)(hA * 128 + rh * 64 + lane);
            const int gcolb = to * 128 + g * 16;   // byte col in 512B row
            stage16((const char*)Ab + (size_t)(bm + grow) * (NFP * 2) + gcolb,
                    smem + ca * 1024);
            stage16((const char*)Bb + (size_t)(bn + grow) * (NFP * 2) + gcolb,
                    smem + 32768 + ca * 1024);
        }
        SB();
        asm volatile("s_waitcnt vmcnt(0)" ::: "memory");
        __builtin_amdgcn_s_barrier();
        SB();

        const char* Abuf = smem + wm * 16384;
        const char* Bbuf = smem + 32768 + (wn >> 1) * 16384;
        const int coff = ((wn & 1) * 64) * 16;
        #pragma unroll
        for (int ks = 0; ks < 4; ++ks) {
            short8 a[4], b[2];
            const int gk = (ks * 2 + kh) * 2048;
            #pragma unroll
            for (int m = 0; m < 4; ++m)
                a[m] = *(const short8*)(Abuf + gk + (m * 32 + l31) * 16);
            #pragma unroll
            for (int n = 0; n < 2; ++n)
                b[n] = *(const short8*)(Bbuf + gk + coff + (n * 32 + l31) * 16);
            __builtin_amdgcn_s_setprio(1);
            #pragma unroll
            for (int m = 0; m < 4; ++m)
                #pragma unroll
                for (int n = 0; n < 2; ++n)
                    accf[m][n] = __builtin_amdgcn_mfma_f32_32x32x16_bf16(
                        a[m], b[n], accf[m][n], 0, 0, 0);
            __builtin_amdgcn_s_setprio(0);
        }
        SB();
        asm volatile("s_waitcnt lgkmcnt(0)" ::: "memory");
        __builtin_amdgcn_s_barrier();
        SB();
    }

    // epilogue: 32x32 C/D layout col=lane&31, row=(r&3)+8*(r>>2)+4*(lane>>5)
    float csv[2], biv[2];
    int colv[2];
    #pragma unroll
    for (int n = 0; n < 2; ++n) {
        colv[n] = bn + wn * 64 + n * 32 + l31;
        csv[n] = cscale[colv[n]];
        biv[n] = bias[colv[n]];
    }
    #pragma unroll
    for (int m = 0; m < 4; ++m) {
        #pragma unroll
        for (int r = 0; r < 16; ++r) {
            const int row = bm + wm * 128 + m * 32 + (r & 3) + 8 * (r >> 2) + 4 * kh;
            const float rs = rscale[row];
            #pragma unroll
            for (int n = 0; n < 2; ++n)
                out[(size_t)row * OUT_F + colv[n]] =
                    accf[m][n][r] * rs * csv[n] + biv[n];
        }
    }
}

// ---------------------------------------------------------------------------
extern "C" void kernel_launch(void* const* d_in, const int* in_sizes, int n_in,
                              void* d_out, int out_size, void* d_ws, size_t ws_size,
                              hipStream_t stream)
{
    const float* x         = (const float*)d_in[0];
    const int*   q_weight  = (const int*)d_in[1];    // int32 on device
    const float* scale_col = (const float*)d_in[2];
    const float* bias      = (const float*)d_in[3];
    const int*   ind       = (const int*)d_in[4];
    float*       out       = (float*)d_out;

    // workspace (~57 MB)
    char*           qx   = (char*)d_ws;                              // M x IN_F i8
    char*           qb   = qx + (size_t)M_DIM * IN_F;                // OUT_F x IN_F i8
    __hip_bfloat16* acts = (__hip_bfloat16*)(qb + (size_t)OUT_F * IN_F);  // M x NFP
    __hip_bfloat16* wob  = acts + (size_t)M_DIM * NFP;               // OUT_F x NFP
    float*          xs   = (float*)(wob + (size_t)OUT_F * NFP);      // M

    const size_t need = (size_t)((char*)(xs + M_DIM) - (char*)d_ws);
    if (ws_size < need) return;

    quant_rows<<<dim3(M_DIM), dim3(256), 0, stream>>>(x, ind, qx, acts, xs);
    conv_w<<<dim3(OUT_F), dim3(256), 0, stream>>>(q_weight, ind, qb, wob);

    gemm_mix<<<dim3((M_DIM / 256) * (OUT_F / 256)), dim3(512), 0, stream>>>(
        qx, qb, (const short*)acts, (const short*)wob,
        xs, scale_col, bias, out);
}